// Round 12
// baseline (591.132 us; speedup 1.0000x reference)
//
#include <hip/hip_runtime.h>
#include <hip/hip_bf16.h>
#include <stdint.h>

typedef __bf16 bf16_t;
typedef __bf16 bf16x4 __attribute__((ext_vector_type(4)));
typedef __bf16 bf16x8 __attribute__((ext_vector_type(8)));
typedef float  f32x4  __attribute__((ext_vector_type(4)));

#define AS_GLOBAL __attribute__((address_space(1)))
#define AS_LDS    __attribute__((address_space(3)))

__device__ __forceinline__ void gload_lds16(const void* g, void* l) {
  __builtin_amdgcn_global_load_lds((const AS_GLOBAL void*)g,
                                   (AS_LDS void*)l, 16, 0, 0);
}

// ---------------- K0a: f32 -> bf16 elementwise (8 elems/thread) ----------------
__global__ void cvt_f32_bf16_kernel(const float* __restrict__ in,
                                    bf16_t* __restrict__ out) {
  const int i = blockIdx.x * blockDim.x + threadIdx.x;
  f32x4 v0 = *(const f32x4*)&in[(size_t)i * 8];
  f32x4 v1 = *(const f32x4*)&in[(size_t)i * 8 + 4];
  bf16x8 o;
  o[0] = (bf16_t)v0[0]; o[1] = (bf16_t)v0[1]; o[2] = (bf16_t)v0[2]; o[3] = (bf16_t)v0[3];
  o[4] = (bf16_t)v1[0]; o[5] = (bf16_t)v1[1]; o[6] = (bf16_t)v1[2]; o[7] = (bf16_t)v1[3];
  *(bf16x8*)&out[(size_t)i * 8] = o;
}

// ---------------- K0b: weight [512][512] f32 -> wT bf16 (transpose) ----------------
__global__ void transpose_cvt_kernel(const float* __restrict__ in,
                                     bf16_t* __restrict__ out) {
  __shared__ float t[32][33];
  const int ti = blockIdx.x;
  const int tj = blockIdx.y;
  const int c = threadIdx.x & 31;
  const int r0 = threadIdx.x >> 5;
  #pragma unroll
  for (int p = 0; p < 4; ++p) {
    int r = r0 + p * 8;
    t[r][c] = in[(size_t)(ti * 32 + r) * 512 + tj * 32 + c];
  }
  __syncthreads();
  #pragma unroll
  for (int p = 0; p < 4; ++p) {
    int r = r0 + p * 8;
    out[(size_t)(tj * 32 + r) * 512 + ti * 32 + c] = (bf16_t)t[c][r];
  }
}

// ---------------- GEMM-BT (R5-proven): C[m][n] (+)= sum_k A[m][k] * Bt[n][k] --
template<int A_IS_F32, int EPI, int NI>
__global__ __launch_bounds__(512, 2) void gemm_bt32_kernel(
    const void* __restrict__ Av, const bf16_t* __restrict__ Bt,
    void* __restrict__ Cv, int nmt, int nnt, int ksteps,
    int lda, int ldb, int ldc, size_t pstride) {
  constexpr int BM = 128, BK = 32, BN = NI * 64;
  __shared__ alignas(16) bf16_t Al[2][BM * BK];
  __shared__ alignas(16) bf16_t Bl[2][BN * BK];

  const int tid  = threadIdx.x;
  const int lane = tid & 63;
  const int w    = tid >> 6;
  const int wr   = w >> 2;
  const int wc   = w & 3;

  const int nwg = gridDim.x;
  const int cpx = nwg >> 3;
  const int bid = blockIdx.x;
  const int swz = (bid & 7) * cpx + (bid >> 3);
  const int ks  = swz / (nmt * nnt);
  const int r_  = swz - ks * (nmt * nnt);
  const int nt  = r_ / nmt;
  const int mt  = r_ - nt * nmt;
  const int row0 = mt * BM;
  const int col0 = nt * BN;
  const int kst  = ks * ksteps * BK;

  f32x4 acc[4][NI];
  #pragma unroll
  for (int mi = 0; mi < 4; ++mi)
    #pragma unroll
    for (int ni = 0; ni < NI; ++ni)
      acc[mi][ni] = (f32x4){0.f, 0.f, 0.f, 0.f};

  const float*  Af = (const float*)Av;
  const bf16_t* Ab = (const bf16_t*)Av;

  const int r4   = tid >> 2;
  const int g4   = tid & 3;
  const int gsrc = g4 ^ (r4 & 3);

  f32x4 apref0, apref1;

  auto stageB = [&](int b, int k0) {
    #pragma unroll
    for (int i = 0; i < NI / 2; ++i)
      gload_lds16(&Bt[(size_t)(col0 + r4 + i * 128) * ldb + kst + k0 + gsrc * 8],
                  &Bl[b][(tid + i * 512) * 8]);
  };
  auto stageA16 = [&](int b, int k0) {
    gload_lds16(&Ab[(size_t)(row0 + r4) * lda + kst + k0 + gsrc * 8],
                &Al[b][tid * 8]);
  };
  auto loadA = [&](int k0) {
    const float* p = &Af[(size_t)(row0 + r4) * lda + kst + k0 + g4 * 8];
    apref0 = *(const f32x4*)p;
    apref1 = *(const f32x4*)(p + 4);
  };
  auto writeA = [&](int b) {
    bf16x8 v;
    v[0] = (bf16_t)apref0[0]; v[1] = (bf16_t)apref0[1];
    v[2] = (bf16_t)apref0[2]; v[3] = (bf16_t)apref0[3];
    v[4] = (bf16_t)apref1[0]; v[5] = (bf16_t)apref1[1];
    v[6] = (bf16_t)apref1[2]; v[7] = (bf16_t)apref1[3];
    *(bf16x8*)&Al[b][r4 * 32 + ((g4 ^ (r4 & 3)) << 3)] = v;
  };

  stageB(0, 0);
  if constexpr (A_IS_F32) {
    loadA(0);
    writeA(0);
    if (ksteps > 1) loadA(BK);
  } else {
    stageA16(0, 0);
  }
  __syncthreads();

  int cur = 0;
  for (int kt = 0; kt < ksteps; ++kt) {
    if (kt + 1 < ksteps) {
      stageB(cur ^ 1, (kt + 1) * BK);
      if constexpr (A_IS_F32) {
        writeA(cur ^ 1);
        if (kt + 2 < ksteps) loadA((kt + 2) * BK);
      } else {
        stageA16(cur ^ 1, (kt + 1) * BK);
      }
    }
    const int frow = lane & 15;
    const int gk = lane >> 4;
    bf16x8 a[4], b[NI];
    #pragma unroll
    for (int mi = 0; mi < 4; ++mi) {
      const int r = wr * 64 + mi * 16 + frow;
      a[mi] = *(const bf16x8*)&Al[cur][r * 32 + ((gk ^ (r & 3)) << 3)];
    }
    #pragma unroll
    for (int ni = 0; ni < NI; ++ni) {
      const int r = wc * (NI * 16) + ni * 16 + frow;
      b[ni] = *(const bf16x8*)&Bl[cur][r * 32 + ((gk ^ (r & 3)) << 3)];
    }
    #pragma unroll
    for (int mi = 0; mi < 4; ++mi)
      #pragma unroll
      for (int ni = 0; ni < NI; ++ni)
        acc[mi][ni] = __builtin_amdgcn_mfma_f32_16x16x32_bf16(a[mi], b[ni], acc[mi][ni], 0, 0, 0);
    __syncthreads();
    cur ^= 1;
  }

  const int rbase = row0 + wr * 64 + ((lane >> 4) << 2);
  const int cbase = col0 + wc * (NI * 16) + (lane & 15);
  if constexpr (EPI == 3) {
    bf16_t* C = (bf16_t*)Cv + (size_t)ks * pstride;
    #pragma unroll
    for (int mi = 0; mi < 4; ++mi)
      #pragma unroll
      for (int ni = 0; ni < NI; ++ni)
        #pragma unroll
        for (int j = 0; j < 4; ++j)
          C[(size_t)(rbase + mi * 16 + j) * ldc + cbase + ni * 16] =
              (bf16_t)acc[mi][ni][j];
  } else if constexpr (EPI == 2) {
    float* C = (float*)Cv;
    #pragma unroll
    for (int mi = 0; mi < 4; ++mi)
      #pragma unroll
      for (int ni = 0; ni < NI; ++ni)
        #pragma unroll
        for (int j = 0; j < 4; ++j)
          atomicAdd(&C[(size_t)(rbase + mi * 16 + j) * ldc + cbase + ni * 16],
                    acc[mi][ni][j]);
  } else {
    bf16_t* C = (bf16_t*)Cv;
    #pragma unroll
    for (int mi = 0; mi < 4; ++mi)
      #pragma unroll
      for (int ni = 0; ni < NI; ++ni)
        #pragma unroll
        for (int j = 0; j < 4; ++j)
          C[(size_t)(rbase + mi * 16 + j) * ldc + cbase + ni * 16] =
              (bf16_t)acc[mi][ni][j];
  }
}

// ================= DIAGNOSTIC PROBES (run after output is final) =============
// All mirror K2's exact geometry: grid 256, 512 thr, BM=128/BN=512/BK=32,
// ks = swz/64, mt = swz%64. Writes go to the spent partial buffer.

// P1: staging pipe only (B gload_lds x4 + A f32 flat->cvt->ds_write), 2x steps.
__global__ __launch_bounds__(512, 2) void probe_stage_f32(
    const float* __restrict__ adj, const bf16_t* __restrict__ Bt,
    bf16_t* __restrict__ sink, int iters) {
  __shared__ alignas(16) bf16_t Al[2][128 * 32];
  __shared__ alignas(16) bf16_t Bl[2][512 * 32];
  const int tid = threadIdx.x;
  const int bid = blockIdx.x;
  const int swz = (bid & 7) * 32 + (bid >> 3);
  const int ks  = swz >> 6;
  const int mt  = swz & 63;
  const int row0 = mt * 128;
  const int kst  = ks * 2048;
  const int r4 = tid >> 2, g4 = tid & 3, gsrc = g4 ^ (r4 & 3);
  f32x4 apref0, apref1;

  auto stageB = [&](int b, int k0) {
    #pragma unroll
    for (int i = 0; i < 4; ++i)
      gload_lds16(&Bt[(size_t)(r4 + i * 128) * 8192 + kst + k0 + gsrc * 8],
                  &Bl[b][(tid + i * 512) * 8]);
  };
  auto loadA = [&](int k0) {
    const float* p = &adj[(size_t)(row0 + r4) * 8192 + kst + k0 + g4 * 8];
    apref0 = *(const f32x4*)p;
    apref1 = *(const f32x4*)(p + 4);
  };
  auto writeA = [&](int b) {
    bf16x8 v;
    v[0] = (bf16_t)apref0[0]; v[1] = (bf16_t)apref0[1];
    v[2] = (bf16_t)apref0[2]; v[3] = (bf16_t)apref0[3];
    v[4] = (bf16_t)apref1[0]; v[5] = (bf16_t)apref1[1];
    v[6] = (bf16_t)apref1[2]; v[7] = (bf16_t)apref1[3];
    *(bf16x8*)&Al[b][r4 * 32 + ((g4 ^ (r4 & 3)) << 3)] = v;
  };

  stageB(0, 0);
  loadA(0); writeA(0); loadA(32);
  __syncthreads();
  int cur = 0;
  for (int t = 0; t < iters; ++t) {
    stageB(cur ^ 1, ((t + 1) & 63) * 32);
    writeA(cur ^ 1);
    loadA(((t + 2) & 63) * 32);
    __syncthreads();
    cur ^= 1;
  }
  bf16x8 a = *(const bf16x8*)&Al[0][tid * 8];
  bf16x8 b = *(const bf16x8*)&Bl[0][tid * 8];
  sink[(size_t)bid * 512 + tid] = a[0] + b[0];
}

// P2: staging with BOTH operands via gload_lds (A = bf16-cast adj), 2x steps.
__global__ __launch_bounds__(512, 2) void probe_stage_bf16(
    const bf16_t* __restrict__ Ab, const bf16_t* __restrict__ Bt,
    bf16_t* __restrict__ sink, int iters) {
  __shared__ alignas(16) bf16_t Al[2][128 * 32];
  __shared__ alignas(16) bf16_t Bl[2][512 * 32];
  const int tid = threadIdx.x;
  const int bid = blockIdx.x;
  const int swz = (bid & 7) * 32 + (bid >> 3);
  const int ks  = swz >> 6;
  const int mt  = swz & 63;
  const int row0 = mt * 128;
  const int kst  = ks * 2048;
  const int r4 = tid >> 2, g4 = tid & 3, gsrc = g4 ^ (r4 & 3);

  auto stageB = [&](int b, int k0) {
    #pragma unroll
    for (int i = 0; i < 4; ++i)
      gload_lds16(&Bt[(size_t)(r4 + i * 128) * 8192 + kst + k0 + gsrc * 8],
                  &Bl[b][(tid + i * 512) * 8]);
  };
  auto stageA = [&](int b, int k0) {
    gload_lds16(&Ab[(size_t)(row0 + r4) * 8192 + kst + k0 + gsrc * 8],
                &Al[b][tid * 8]);
  };

  stageB(0, 0); stageA(0, 0);
  __syncthreads();
  int cur = 0;
  for (int t = 0; t < iters; ++t) {
    stageB(cur ^ 1, ((t + 1) & 63) * 32);
    stageA(cur ^ 1, ((t + 1) & 63) * 32);
    __syncthreads();
    cur ^= 1;
  }
  bf16x8 a = *(const bf16x8*)&Al[0][tid * 8];
  bf16x8 b = *(const bf16x8*)&Bl[0][tid * 8];
  sink[(size_t)bid * 512 + tid] = a[0] + b[0];
}

// P3: compute path only — stage once, then {frag reads + 32 MFMA + barrier}, 4x.
__global__ __launch_bounds__(512, 2) void probe_mfma(
    const bf16_t* __restrict__ Ab, const bf16_t* __restrict__ Bt,
    bf16_t* __restrict__ sink, int iters) {
  __shared__ alignas(16) bf16_t Al[2][128 * 32];
  __shared__ alignas(16) bf16_t Bl[2][512 * 32];
  const int tid = threadIdx.x;
  const int lane = tid & 63;
  const int w = tid >> 6;
  const int wr = w >> 2, wc = w & 3;
  const int bid = blockIdx.x;
  const int swz = (bid & 7) * 32 + (bid >> 3);
  const int ks  = swz >> 6;
  const int mt  = swz & 63;
  const int row0 = mt * 128;
  const int kst  = ks * 2048;
  const int r4 = tid >> 2, g4 = tid & 3, gsrc = g4 ^ (r4 & 3);

  #pragma unroll
  for (int b = 0; b < 2; ++b) {
    #pragma unroll
    for (int i = 0; i < 4; ++i)
      gload_lds16(&Bt[(size_t)(r4 + i * 128) * 8192 + kst + b * 32 + gsrc * 8],
                  &Bl[b][(tid + i * 512) * 8]);
    gload_lds16(&Ab[(size_t)(row0 + r4) * 8192 + kst + b * 32 + gsrc * 8],
                &Al[b][tid * 8]);
  }
  __syncthreads();

  f32x4 acc[4][8];
  #pragma unroll
  for (int mi = 0; mi < 4; ++mi)
    #pragma unroll
    for (int ni = 0; ni < 8; ++ni)
      acc[mi][ni] = (f32x4){0.f, 0.f, 0.f, 0.f};

  const int frow = lane & 15;
  const int gk = lane >> 4;
  int cur = 0;
  for (int t = 0; t < iters; ++t) {
    bf16x8 a[4], b[8];
    #pragma unroll
    for (int mi = 0; mi < 4; ++mi) {
      const int r = wr * 64 + mi * 16 + frow;
      a[mi] = *(const bf16x8*)&Al[cur][r * 32 + ((gk ^ (r & 3)) << 3)];
    }
    #pragma unroll
    for (int ni = 0; ni < 8; ++ni) {
      const int r = wc * 128 + ni * 16 + frow;
      b[ni] = *(const bf16x8*)&Bl[cur][r * 32 + ((gk ^ (r & 3)) << 3)];
    }
    #pragma unroll
    for (int mi = 0; mi < 4; ++mi)
      #pragma unroll
      for (int ni = 0; ni < 8; ++ni)
        acc[mi][ni] = __builtin_amdgcn_mfma_f32_16x16x32_bf16(a[mi], b[ni], acc[mi][ni], 0, 0, 0);
    __syncthreads();
    cur ^= 1;
  }
  float s = 0.f;
  #pragma unroll
  for (int mi = 0; mi < 4; ++mi)
    #pragma unroll
    for (int ni = 0; ni < 8; ++ni)
      s += acc[mi][ni][0] + acc[mi][ni][3];
  sink[(size_t)bid * 512 + tid] = (bf16_t)s;
}

// ---------------- reduce 4 bf16 partials + relu -> f32 ----------------
__global__ void reduce4_relu_kernel(const bf16_t* __restrict__ part,
                                    size_t pstride, float* __restrict__ out) {
  const size_t i8 = ((size_t)blockIdx.x * blockDim.x + threadIdx.x) * 8;
  float s[8];
  #pragma unroll
  for (int j = 0; j < 8; ++j) s[j] = 0.f;
  #pragma unroll
  for (int p = 0; p < 4; ++p) {
    bf16x8 v = *(const bf16x8*)&part[p * pstride + i8];
    #pragma unroll
    for (int j = 0; j < 8; ++j) s[j] += (float)v[j];
  }
  f32x4 r0, r1;
  r0[0] = fmaxf(s[0], 0.f); r0[1] = fmaxf(s[1], 0.f);
  r0[2] = fmaxf(s[2], 0.f); r0[3] = fmaxf(s[3], 0.f);
  r1[0] = fmaxf(s[4], 0.f); r1[1] = fmaxf(s[5], 0.f);
  r1[2] = fmaxf(s[6], 0.f); r1[3] = fmaxf(s[7], 0.f);
  *(f32x4*)&out[i8] = r0;
  *(f32x4*)&out[i8 + 4] = r1;
}

// ---------------- in-place relu (atomic fallback) ----------------
__global__ void relu_inplace_kernel(float* __restrict__ out) {
  const size_t i = ((size_t)blockIdx.x * blockDim.x + threadIdx.x) * 4;
  f32x4 a = *(const f32x4*)&out[i];
  f32x4 r;
  r[0] = fmaxf(a[0], 0.f); r[1] = fmaxf(a[1], 0.f);
  r[2] = fmaxf(a[2], 0.f); r[3] = fmaxf(a[3], 0.f);
  *(f32x4*)&out[i] = r;
}

extern "C" void kernel_launch(void* const* d_in, const int* in_sizes, int n_in,
                              void* d_out, int out_size, void* d_ws, size_t ws_size,
                              hipStream_t stream) {
  const int N = 8192, D = 512;
  const float* features = (const float*)d_in[0];  // [N][D]
  const float* adj      = (const float*)d_in[1];  // [N][N]
  const float* weight   = (const float*)d_in[2];  // [D][D]
  float* out = (float*)d_out;                     // [N][D] f32

  char* ws = (char*)d_ws;
  bf16_t* fb16 = (bf16_t*)ws;                                    // 8.39 MB
  bf16_t* wT   = (bf16_t*)(ws + (size_t)N * D * 2);              // 0.52 MB
  bf16_t* fwT  = (bf16_t*)(ws + (size_t)N * D * 2 + (size_t)D * D * 2);  // 8.39 MB
  const size_t base_bytes = (size_t)N * D * 2 * 2 + (size_t)D * D * 2;   // 17.3 MB
  bf16_t* part = (bf16_t*)(ws + base_bytes);      // 4 x 8.39 MB bf16 partials
  const size_t pstride = (size_t)N * D;
  const bool have_part = ws_size >= base_bytes + 4 * pstride * sizeof(bf16_t);

  // K0a: features f32 -> bf16
  cvt_f32_bf16_kernel<<<(N * D / 8) / 256, 256, 0, stream>>>(features, fb16);
  // K0b: wT[dout][din] = weight[din][dout]
  transpose_cvt_kernel<<<dim3(16, 16), 256, 0, stream>>>(weight, wT);
  // K1: fwT[dout][node] = wT @ fb16^T
  gemm_bt32_kernel<0, 0, 2><<<256, 512, 0, stream>>>(wT, fb16, fwT,
                                                     4, 64, 16, 512, 512, 8192, 0);
  // K2 (R5 config — best known): BM=128, BN=512, k-split 4, grid 256
  if (have_part) {
    gemm_bt32_kernel<1, 3, 8><<<256, 512, 0, stream>>>(adj, fwT, part,
                                                       64, 1, 64, 8192, 8192, 512, pstride);
    reduce4_relu_kernel<<<(N * D / 8) / 512, 512, 0, stream>>>(part, pstride, out);
    // ---- diagnostics (output already final; sinks overwrite spent partials) ----
    probe_stage_f32<<<256, 512, 0, stream>>>(adj, fwT, part, 128);
    probe_stage_bf16<<<256, 512, 0, stream>>>((const bf16_t*)adj, fwT,
                                              part + (size_t)256 * 512, 128);
    probe_mfma<<<256, 512, 0, stream>>>((const bf16_t*)adj, fwT,
                                        part + (size_t)2 * 256 * 512, 256);
  } else {
    hipMemsetAsync(d_out, 0, (size_t)N * D * sizeof(float), stream);
    gemm_bt32_kernel<1, 2, 8><<<256, 512, 0, stream>>>(adj, fwT, out,
                                                       64, 1, 64, 8192, 8192, 512, 0);
    relu_inplace_kernel<<<(N * D / 4) / 512, 512, 0, stream>>>(out);
  }
}

// Round 13
// 164.200 us; speedup vs baseline: 3.6001x; 3.6001x over previous
//
#include <hip/hip_runtime.h>
#include <hip/hip_bf16.h>
#include <stdint.h>

typedef __bf16 bf16_t;
typedef __bf16 bf16x4 __attribute__((ext_vector_type(4)));
typedef __bf16 bf16x8 __attribute__((ext_vector_type(8)));
typedef float  f32x4  __attribute__((ext_vector_type(4)));

#define AS_GLOBAL __attribute__((address_space(1)))
#define AS_LDS    __attribute__((address_space(3)))

__device__ __forceinline__ void gload_lds16(const void* g, void* l) {
  __builtin_amdgcn_global_load_lds((const AS_GLOBAL void*)g,
                                   (AS_LDS void*)l, 16, 0, 0);
}

// ---------------- K0a: f32 -> bf16 elementwise (8 elems/thread) ----------------
__global__ void cvt_f32_bf16_kernel(const float* __restrict__ in,
                                    bf16_t* __restrict__ out) {
  const int i = blockIdx.x * blockDim.x + threadIdx.x;
  f32x4 v0 = *(const f32x4*)&in[(size_t)i * 8];
  f32x4 v1 = *(const f32x4*)&in[(size_t)i * 8 + 4];
  bf16x8 o;
  o[0] = (bf16_t)v0[0]; o[1] = (bf16_t)v0[1]; o[2] = (bf16_t)v0[2]; o[3] = (bf16_t)v0[3];
  o[4] = (bf16_t)v1[0]; o[5] = (bf16_t)v1[1]; o[6] = (bf16_t)v1[2]; o[7] = (bf16_t)v1[3];
  *(bf16x8*)&out[(size_t)i * 8] = o;
}

// ---------------- K0b: weight [512][512] f32 -> wT bf16 (transpose) ----------------
__global__ void transpose_cvt_kernel(const float* __restrict__ in,
                                     bf16_t* __restrict__ out) {
  __shared__ float t[32][33];
  const int ti = blockIdx.x;
  const int tj = blockIdx.y;
  const int c = threadIdx.x & 31;
  const int r0 = threadIdx.x >> 5;
  #pragma unroll
  for (int p = 0; p < 4; ++p) {
    int r = r0 + p * 8;
    t[r][c] = in[(size_t)(ti * 32 + r) * 512 + tj * 32 + c];
  }
  __syncthreads();
  #pragma unroll
  for (int p = 0; p < 4; ++p) {
    int r = r0 + p * 8;
    out[(size_t)(tj * 32 + r) * 512 + ti * 32 + c] = (bf16_t)t[c][r];
  }
}

// ---------------- K1 GEMM-BT (bf16 A, stage-ahead dbuf, R5-proven) ------------
// EPI 4: store output PACKED granule-major: fwP[node>>3][dout][8] bf16 —
// the layout K2 reads B from directly (coalesced L2 hits, no LDS staging).
template<int EPI, int NI>
__global__ __launch_bounds__(512, 2) void gemm_bt32_kernel(
    const bf16_t* __restrict__ Ab, const bf16_t* __restrict__ Bt,
    bf16_t* __restrict__ Cv, int nmt, int nnt, int ksteps,
    int lda, int ldb, int ldc) {
  constexpr int BM = 128, BK = 32, BN = NI * 64;
  __shared__ alignas(16) bf16_t Al[2][BM * BK];
  __shared__ alignas(16) bf16_t Bl[2][BN * BK];

  const int tid  = threadIdx.x;
  const int lane = tid & 63;
  const int w    = tid >> 6;
  const int wr   = w >> 2;
  const int wc   = w & 3;

  const int nwg = gridDim.x;
  const int cpx = nwg >> 3;
  const int bid = blockIdx.x;
  const int swz = (bid & 7) * cpx + (bid >> 3);
  const int nt  = swz / nmt;
  const int mt  = swz - nt * nmt;
  const int row0 = mt * BM;
  const int col0 = nt * BN;

  f32x4 acc[4][NI];
  #pragma unroll
  for (int mi = 0; mi < 4; ++mi)
    #pragma unroll
    for (int ni = 0; ni < NI; ++ni)
      acc[mi][ni] = (f32x4){0.f, 0.f, 0.f, 0.f};

  const int r4   = tid >> 2;
  const int g4   = tid & 3;
  const int gsrc = g4 ^ (r4 & 3);

  auto stageB = [&](int b, int k0) {
    #pragma unroll
    for (int i = 0; i < NI / 2; ++i)
      gload_lds16(&Bt[(size_t)(col0 + r4 + i * 128) * ldb + k0 + gsrc * 8],
                  &Bl[b][(tid + i * 512) * 8]);
  };
  auto stageA = [&](int b, int k0) {
    gload_lds16(&Ab[(size_t)(row0 + r4) * lda + k0 + gsrc * 8],
                &Al[b][tid * 8]);
  };

  stageB(0, 0);
  stageA(0, 0);
  __syncthreads();

  int cur = 0;
  for (int kt = 0; kt < ksteps; ++kt) {
    if (kt + 1 < ksteps) {
      stageB(cur ^ 1, (kt + 1) * BK);
      stageA(cur ^ 1, (kt + 1) * BK);
    }
    const int frow = lane & 15;
    const int gk = lane >> 4;
    bf16x8 a[4], b[NI];
    #pragma unroll
    for (int mi = 0; mi < 4; ++mi) {
      const int r = wr * 64 + mi * 16 + frow;
      a[mi] = *(const bf16x8*)&Al[cur][r * 32 + ((gk ^ (r & 3)) << 3)];
    }
    #pragma unroll
    for (int ni = 0; ni < NI; ++ni) {
      const int r = wc * (NI * 16) + ni * 16 + frow;
      b[ni] = *(const bf16x8*)&Bl[cur][r * 32 + ((gk ^ (r & 3)) << 3)];
    }
    #pragma unroll
    for (int mi = 0; mi < 4; ++mi)
      #pragma unroll
      for (int ni = 0; ni < NI; ++ni)
        acc[mi][ni] = __builtin_amdgcn_mfma_f32_16x16x32_bf16(a[mi], b[ni], acc[mi][ni], 0, 0, 0);
    __syncthreads();
    cur ^= 1;
  }

  const int rbase = row0 + wr * 64 + ((lane >> 4) << 2);
  const int cbase = col0 + wc * (NI * 16) + (lane & 15);
  if constexpr (EPI == 4) {       // packed granule-major: [col>>3][row][col&7]
    #pragma unroll
    for (int mi = 0; mi < 4; ++mi)
      #pragma unroll
      for (int ni = 0; ni < NI; ++ni)
        #pragma unroll
        for (int j = 0; j < 4; ++j) {
          const int col = cbase + ni * 16;
          const int row = rbase + mi * 16 + j;
          Cv[((size_t)(col >> 3) * 512 + row) * 8 + (col & 7)] =
              (bf16_t)acc[mi][ni][j];
        }
  } else {
    #pragma unroll
    for (int mi = 0; mi < 4; ++mi)
      #pragma unroll
      for (int ni = 0; ni < NI; ++ni)
        #pragma unroll
        for (int j = 0; j < 4; ++j)
          Cv[(size_t)(rbase + mi * 16 + j) * ldc + cbase + ni * 16] =
              (bf16_t)acc[mi][ni][j];
  }
}

// ---------------- K2 v4: adj(f32) @ fwP — A-only LDS, B direct from L2 -------
// BM=128, BN=512, BK=32, k-split 4 -> grid 256, 512 thr = 8 waves (2M x 4N),
// wave tile 64x128, acc[4][8].
// A: f32, 4-deep LDS multibuffer (4 x 16 KB) via global_load_lds (2/thread/
//    step, source-granule preswizzled g^(row&7)); cvt f32->bf16 at frag-read.
// B: NO LDS — direct bf16x8 loads from fwP[granule][dout][8] (L2-resident
//    2.1 MB slice per ks; 16-lane groups read 256 B contiguous). Issued BEFORE
//    the A-stage each step, so the compiler's own B-wait (vmcnt small) drains
//    A two steps ahead — free 2-deep A pipeline, no vmcnt(0) anywhere.
// Raw s_barrier once per step bounds wave skew (4 buffers make write/read
// phases disjoint). Diagnosis (R12 probes): staging was 100% of K2's critical
// path; this removes 2/3 of staged bytes and all barrier-coupled drains.
template<int EPI>  // 3: bf16 partial @ Cv+ks*pstride; 2: f32 atomicAdd
__global__ __launch_bounds__(512, 2) void gemm_k2_v4(
    const float* __restrict__ adj, const bf16_t* __restrict__ Bp,
    void* __restrict__ Cv, size_t pstride) {
  constexpr int NT = 64;
  __shared__ alignas(16) float As[4][128 * 32];   // 4 x 16 KB

  const int tid  = threadIdx.x;
  const int lane = tid & 63;
  const int w    = tid >> 6;
  const int wr   = w >> 2;   // 0..1
  const int wc   = w & 3;    // 0..3

  const int bid = blockIdx.x;                 // grid 256
  const int swz = (bid & 7) * 32 + (bid >> 3);
  const int ks  = swz >> 6;                   // 0..3
  const int mt  = swz & 63;                   // 0..63
  const int row0 = mt * 128;
  const int kbase = ks * 2048;

  f32x4 acc[4][8];
  #pragma unroll
  for (int mi = 0; mi < 4; ++mi)
    #pragma unroll
    for (int ni = 0; ni < 8; ++ni)
      acc[mi][ni] = (f32x4){0.f, 0.f, 0.f, 0.f};

  // A staging: tile 128 rows x 32 f32 = 1024 granules (16 B = 4 f32).
  // granule d in {tid, tid+512}: row = d>>3, slot = d&7; source granule
  // = slot ^ (row&7)  (row&7 invariant under +64).
  const int ar  = tid >> 3;          // 0..63
  const int ags = (tid & 7) ^ (ar & 7);

  auto stageA = [&](int t, int b) {
    const float* p = &adj[(size_t)(row0 + ar) * 8192 + kbase + t * 32 + ags * 4];
    gload_lds16(p, &As[b][tid * 4]);
    gload_lds16(p + (size_t)64 * 8192, &As[b][(tid + 512) * 4]);
  };

  // ---- prologue: 3 stages in flight, wait only for stage 0 ----
  stageA(0, 0);
  stageA(1, 1);
  stageA(2, 2);
  asm volatile("s_waitcnt vmcnt(4)" ::: "memory");
  asm volatile("s_barrier" ::: "memory");

  const int frow = lane & 15;
  const int gk   = lane >> 4;
  const int pbase = (kbase >> 3);    // granule-plane base for this ks

  for (int t = 0; t < NT; ++t) {
    // B fragments: direct from L2-resident packed fwP (no barrier coupling)
    const size_t gp = (size_t)(pbase + t * 4 + gk) * 512;
    bf16x8 b[8];
    #pragma unroll
    for (int ni = 0; ni < 8; ++ni)
      b[ni] = *(const bf16x8*)&Bp[(gp + wc * 128 + ni * 16 + frow) * 8];
    // issue next A stage AFTER B loads: compiler's B-wait leaves A in flight
    if (t + 3 < NT) stageA(t + 3, (t + 3) & 3);
    // A fragments from LDS f32, cvt to bf16
    const int cb = t & 3;
    bf16x8 a[4];
    #pragma unroll
    for (int mi = 0; mi < 4; ++mi) {
      const int r = wr * 64 + mi * 16 + frow;
      f32x4 f0 = *(const f32x4*)&As[cb][r * 32 + (((2 * gk) ^ (frow & 7)) << 2)];
      f32x4 f1 = *(const f32x4*)&As[cb][r * 32 + (((2 * gk + 1) ^ (frow & 7)) << 2)];
      bf16x8 av;
      av[0] = (bf16_t)f0[0]; av[1] = (bf16_t)f0[1];
      av[2] = (bf16_t)f0[2]; av[3] = (bf16_t)f0[3];
      av[4] = (bf16_t)f1[0]; av[5] = (bf16_t)f1[1];
      av[6] = (bf16_t)f1[2]; av[7] = (bf16_t)f1[3];
      a[mi] = av;
    }
    #pragma unroll
    for (int mi = 0; mi < 4; ++mi)
      #pragma unroll
      for (int ni = 0; ni < 8; ++ni)
        acc[mi][ni] = __builtin_amdgcn_mfma_f32_16x16x32_bf16(a[mi], b[ni], acc[mi][ni], 0, 0, 0);
    asm volatile("s_barrier" ::: "memory");
  }

  // epilogue: C/D layout col=lane&15, row=(lane>>4)*4+reg  [m89-verified]
  const int rbase = row0 + wr * 64 + ((lane >> 4) << 2);
  const int cbase = wc * 128 + (lane & 15);
  if constexpr (EPI == 3) {
    bf16_t* C = (bf16_t*)Cv + (size_t)ks * pstride;
    #pragma unroll
    for (int mi = 0; mi < 4; ++mi)
      #pragma unroll
      for (int ni = 0; ni < 8; ++ni)
        #pragma unroll
        for (int j = 0; j < 4; ++j)
          C[(size_t)(rbase + mi * 16 + j) * 512 + cbase + ni * 16] =
              (bf16_t)acc[mi][ni][j];
  } else {
    float* C = (float*)Cv;
    #pragma unroll
    for (int mi = 0; mi < 4; ++mi)
      #pragma unroll
      for (int ni = 0; ni < 8; ++ni)
        #pragma unroll
        for (int j = 0; j < 4; ++j)
          atomicAdd(&C[(size_t)(rbase + mi * 16 + j) * 512 + cbase + ni * 16],
                    acc[mi][ni][j]);
  }
}

// ---------------- reduce 4 bf16 partials + relu -> f32 ----------------
__global__ void reduce4_relu_kernel(const bf16_t* __restrict__ part,
                                    size_t pstride, float* __restrict__ out) {
  const size_t i8 = ((size_t)blockIdx.x * blockDim.x + threadIdx.x) * 8;
  float s[8];
  #pragma unroll
  for (int j = 0; j < 8; ++j) s[j] = 0.f;
  #pragma unroll
  for (int p = 0; p < 4; ++p) {
    bf16x8 v = *(const bf16x8*)&part[p * pstride + i8];
    #pragma unroll
    for (int j = 0; j < 8; ++j) s[j] += (float)v[j];
  }
  f32x4 r0, r1;
  r0[0] = fmaxf(s[0], 0.f); r0[1] = fmaxf(s[1], 0.f);
  r0[2] = fmaxf(s[2], 0.f); r0[3] = fmaxf(s[3], 0.f);
  r1[0] = fmaxf(s[4], 0.f); r1[1] = fmaxf(s[5], 0.f);
  r1[2] = fmaxf(s[6], 0.f); r1[3] = fmaxf(s[7], 0.f);
  *(f32x4*)&out[i8] = r0;
  *(f32x4*)&out[i8 + 4] = r1;
}

// ---------------- in-place relu (atomic fallback) ----------------
__global__ void relu_inplace_kernel(float* __restrict__ out) {
  const size_t i = ((size_t)blockIdx.x * blockDim.x + threadIdx.x) * 4;
  f32x4 a = *(const f32x4*)&out[i];
  f32x4 r;
  r[0] = fmaxf(a[0], 0.f); r[1] = fmaxf(a[1], 0.f);
  r[2] = fmaxf(a[2], 0.f); r[3] = fmaxf(a[3], 0.f);
  *(f32x4*)&out[i] = r;
}

extern "C" void kernel_launch(void* const* d_in, const int* in_sizes, int n_in,
                              void* d_out, int out_size, void* d_ws, size_t ws_size,
                              hipStream_t stream) {
  const int N = 8192, D = 512;
  const float* features = (const float*)d_in[0];  // [N][D]
  const float* adj      = (const float*)d_in[1];  // [N][N]
  const float* weight   = (const float*)d_in[2];  // [D][D]
  float* out = (float*)d_out;                     // [N][D] f32

  char* ws = (char*)d_ws;
  bf16_t* fb16 = (bf16_t*)ws;                                    // 8.39 MB
  bf16_t* wT   = (bf16_t*)(ws + (size_t)N * D * 2);              // 0.52 MB
  bf16_t* fwP  = (bf16_t*)(ws + (size_t)N * D * 2 + (size_t)D * D * 2);  // 8.39 MB packed
  const size_t base_bytes = (size_t)N * D * 2 * 2 + (size_t)D * D * 2;   // 17.3 MB
  bf16_t* part = (bf16_t*)(ws + base_bytes);      // 4 x 8.39 MB bf16 partials
  const size_t pstride = (size_t)N * D;
  const bool have_part = ws_size >= base_bytes + 4 * pstride * sizeof(bf16_t);

  // K0a: features f32 -> bf16
  cvt_f32_bf16_kernel<<<(N * D / 8) / 256, 256, 0, stream>>>(features, fb16);
  // K0b: wT[dout][din] = weight[din][dout]
  transpose_cvt_kernel<<<dim3(16, 16), 256, 0, stream>>>(weight, wT);
  // K1: fwP[node>>3][dout][8] = (wT @ fb16^T) packed granule-major
  gemm_bt32_kernel<4, 2><<<256, 512, 0, stream>>>(wT, fb16, fwP,
                                                  4, 64, 16, 512, 512, 8192);
  // K2: relu(adj @ fw^T) via v4 (A-only LDS, B direct), k-split 4, grid 256
  if (have_part) {
    gemm_k2_v4<3><<<256, 512, 0, stream>>>(adj, fwP, part, pstride);
    reduce4_relu_kernel<<<(N * D / 8) / 512, 512, 0, stream>>>(part, pstride, out);
  } else {
    hipMemsetAsync(d_out, 0, (size_t)N * D * sizeof(float), stream);
    gemm_k2_v4<2><<<256, 512, 0, stream>>>(adj, fwP, out, 0);
    relu_inplace_kernel<<<(N * D / 4) / 512, 512, 0, stream>>>(out);
  }
}